// Round 9
// baseline (50.247 us; speedup 1.0000x reference)
//
#include <hip/hip_runtime.h>

#define W 512

typedef float v4f __attribute__((ext_vector_type(4)));   // clang vector: valid for nt builtins

// ---------------------------------------------------------------------------
// Fused kernel, 1024 threads = 16 waves per block.
//
// R2-R7 lesson: every attempt to make the col scan register-resident across
// the barrier ends up as a 2-pass with the re-read served by L2/L3 — all at
// 43-45 us. The re-read is NOT the limiter. The limiter is the HBM stream:
// our 128 MB of output writes evict the 128 MB input from the 256 MB L3
// between graph replays (FETCH_SIZE = 64 MB = half the input re-fetched).
//
// R9 change (R8 fixed): all output stores NON-TEMPORAL via clang ext-vector
// v4f (HIP float4 is a class type the builtin rejects). No L2/L3 allocation
// for the write stream -> input stays L3-resident across replays.
//
// Blocks [0, B*4):  column scan (channel 1), float4-vectorized, explicit
//   2-pass. Tile = 128 cols x 512 rows; thread (c4=t&31, seg=t>>5) owns
//   4 cols x 16 rows. Phase 1: segment sum. LDS exchange. Phase 2: reload
//   (L2/L3-hot), running scan with offset, nt store.
// Blocks [B*4, ...): row scan (channel 0). One wave per 512-float row,
//   2x v4f per lane, local scan of 8 + 6-step __shfl_up wave scan.
// ---------------------------------------------------------------------------
__global__ __launch_bounds__(1024) void fused_scan_kernel(const float* __restrict__ in,
                                                          float* __restrict__ out,
                                                          int B) {
    __shared__ v4f sums[32][32];    // [segment][c4]  (16 KiB)

    const int nColBlocks = B * 4;   // 128-col tiles per image

    if ((int)blockIdx.x < nColBlocks) {
        // ----- column scan (channel 1) -----
        const int tile = blockIdx.x & 3;
        const int b    = blockIdx.x >> 2;
        const int c4   = threadIdx.x & 31;     // float4 column group
        const int seg  = threadIdx.x >> 5;     // 0..31, 16 rows each
        const int col  = tile * 128 + c4 * 4;

        const size_t base = (size_t)b * (2 * W * W) + (size_t)(W * W) + col
                          + (size_t)(seg * 16) * W;
        const v4f* __restrict__ p = (const v4f*)(in + base);
        v4f*       __restrict__ q = (v4f*)(out + base);
        const int strideV = W / 4;             // row stride in v4f units

        // Phase 1: segment sum (loads consumed immediately, high MLP)
        v4f acc = (v4f)(0.f);
#pragma unroll
        for (int y = 0; y < 16; ++y) {
            acc += p[(size_t)y * strideV];
        }
        sums[seg][c4] = acc;
        __syncthreads();

        // Exclusive offset = sum of preceding segments' totals
        v4f off = (v4f)(0.f);
        for (int s = 0; s < seg; ++s) off += sums[s][c4];

        // Phase 2: reload (L2/L3-hot), running scan, non-temporal store
#pragma unroll
        for (int y = 0; y < 16; ++y) {
            off += p[(size_t)y * strideV];
            __builtin_nontemporal_store(off, &q[(size_t)y * strideV]);
        }
    } else {
        // ----- row scan (channel 0) -----
        const int tx  = threadIdx.x & 63;      // lane
        const int wv  = threadIdx.x >> 6;      // wave 0..15
        const int rb  = (int)blockIdx.x - nColBlocks;
        const int row = rb * 16 + wv;          // global row in [0, B*W)
        const int b   = row >> 9;              // / 512
        const int y   = row & 511;             // % 512
        const size_t base = (size_t)b * (2 * W * W) + (size_t)y * W;

        const v4f* __restrict__ ip = (const v4f*)(in + base);
        v4f v0 = ip[tx * 2 + 0];
        v4f v1 = ip[tx * 2 + 1];

        float a0 = v0.x;
        float a1 = a0 + v0.y;
        float a2 = a1 + v0.z;
        float a3 = a2 + v0.w;
        float a4 = a3 + v1.x;
        float a5 = a4 + v1.y;
        float a6 = a5 + v1.z;
        float a7 = a6 + v1.w;

        float total = a7;
        float inc = total;
#pragma unroll
        for (int o = 1; o < 64; o <<= 1) {
            float t = __shfl_up(inc, o, 64);
            if (tx >= o) inc += t;
        }
        const float excl = inc - total;

        v4f r0 = { a0 + excl, a1 + excl, a2 + excl, a3 + excl };
        v4f r1 = { a4 + excl, a5 + excl, a6 + excl, a7 + excl };

        v4f* __restrict__ op = (v4f*)(out + base);
        __builtin_nontemporal_store(r0, &op[tx * 2 + 0]);
        __builtin_nontemporal_store(r1, &op[tx * 2 + 1]);
    }
}

extern "C" void kernel_launch(void* const* d_in, const int* in_sizes, int n_in,
                              void* d_out, int out_size, void* d_ws, size_t ws_size,
                              hipStream_t stream) {
    const float* in = (const float*)d_in[0];
    float* out = (float*)d_out;

    const int B = in_sizes[0] / (2 * W * W);   // 64
    const int colBlocks = B * 4;               // 256  (128-col float4 tiles)
    const int rowBlocks = (B * W) / 16;        // 2048 (16 rows per block)

    fused_scan_kernel<<<colBlocks + rowBlocks, 1024, 0, stream>>>(in, out, B);
}